// Round 1
// baseline (313.188 us; speedup 1.0000x reference)
//
#include <hip/hip_runtime.h>
#include <math.h>

// DNC single step, MI355X. All f32. B=16,N=2048,M=64,R=4,H=512.
constexpr int BB = 16, NN = 2048, MM = 64, RR = 4, HH = 512;
constexpr int CIN = 320, COUT = 535;
constexpr int CHUNKS = 32, ROWS = 64; // link kernel row-chunking

// ---- output layout (floats): output, memory_new, link_new, p_new, usage, read_w
constexpr size_t O_OUT   = 0;
constexpr size_t O_MEM   = O_OUT + (size_t)BB * 64;                 // 1024
constexpr size_t O_LINK  = O_MEM + (size_t)BB * NN * MM;            // 2098176
constexpr size_t O_PNEW  = O_LINK + (size_t)BB * NN * NN;           // 69207040
constexpr size_t O_USAGE = O_PNEW + (size_t)BB * NN;
constexpr size_t O_READW = O_USAGE + (size_t)BB * NN;

// ---- workspace layout (floats) — total ~4.92M floats ~19.7 MB
constexpr size_t WS_GATES = 0;                                   // B*2048
constexpr size_t WS_H     = WS_GATES + (size_t)BB * 4 * HH;      // B*512
constexpr size_t WS_OUTR  = WS_H + (size_t)BB * HH;              // B*535
constexpr size_t WS_TASK  = WS_OUTR + (size_t)BB * COUT;         // B*64
constexpr size_t WS_RKEYS = WS_TASK + (size_t)BB * 64;           // B*256
constexpr size_t WS_RBETA = WS_RKEYS + (size_t)BB * 256;         // B*4
constexpr size_t WS_FGATE = WS_RBETA + (size_t)BB * 4;           // B*4
constexpr size_t WS_WKEY  = WS_FGATE + (size_t)BB * 4;           // B*64
constexpr size_t WS_WBETA = WS_WKEY + (size_t)BB * 64;           // B
constexpr size_t WS_ERASE = WS_WBETA + (size_t)BB;               // B*64
constexpr size_t WS_WVEC  = WS_ERASE + (size_t)BB * 64;          // B*64
constexpr size_t WS_AGATE = WS_WVEC + (size_t)BB * 64;           // B
constexpr size_t WS_WGATE = WS_AGATE + (size_t)BB;               // B
constexpr size_t WS_MODES = WS_WGATE + (size_t)BB;               // B*12
constexpr size_t WS_KN    = WS_MODES + (size_t)BB * 12;          // B*5
constexpr size_t WS_SCORE = WS_KN + (size_t)BB * 5;              // B*5*N
constexpr size_t WS_CONT  = WS_SCORE + (size_t)BB * 5 * NN;      // B*5*N
constexpr size_t WS_ALLOC = WS_CONT + (size_t)BB * 5 * NN;       // B*N
constexpr size_t WS_WW    = WS_ALLOC + (size_t)BB * NN;          // B*N
constexpr size_t WS_FWD   = WS_WW + (size_t)BB * NN;             // B*4*N
constexpr size_t WS_BWD   = WS_FWD + (size_t)BB * 4 * NN;        // B*4*N
constexpr size_t WS_BPART = WS_BWD + (size_t)BB * 4 * NN;        // B*CHUNKS*4*N = 4194304
constexpr size_t WS_READS = WS_BPART + (size_t)BB * CHUNKS * 4 * NN; // B*256
constexpr size_t WS_TOTAL = WS_READS + (size_t)BB * 256;

__device__ __forceinline__ float sigf(float x) { return 1.0f / (1.0f + expf(-x)); }
__device__ __forceinline__ float oneplusf(float x) {
  // 1 + softplus(x), numerically stable
  return 1.0f + fmaxf(x, 0.0f) + log1pf(expf(-fabsf(x)));
}

// ---- K1: gates = x @ W_ih^T + h_prev @ W_hh^T + b_lstm  (one wave per row j)
__global__ void k_gates(const float* __restrict__ task, const float* __restrict__ prev_reads,
                        const float* __restrict__ h_prev, const float* __restrict__ W_ih,
                        const float* __restrict__ W_hh, const float* __restrict__ b_lstm,
                        float* __restrict__ ws) {
  int tid = threadIdx.x, lane = tid & 63, wave = tid >> 6;
  int j = blockIdx.x * 4 + wave; // 0..2047
  float acc[16];
#pragma unroll
  for (int b = 0; b < 16; b++) acc[b] = 0.f;
#pragma unroll
  for (int s = 0; s < 5; s++) {
    int k = s * 64 + lane;
    float wv = W_ih[j * CIN + k];
    if (s == 0) {
#pragma unroll
      for (int b = 0; b < 16; b++) acc[b] += wv * task[b * 64 + k];
    } else {
#pragma unroll
      for (int b = 0; b < 16; b++) acc[b] += wv * prev_reads[b * 256 + (k - 64)];
    }
  }
#pragma unroll
  for (int s = 0; s < 8; s++) {
    int k = s * 64 + lane;
    float wv = W_hh[j * HH + k];
#pragma unroll
    for (int b = 0; b < 16; b++) acc[b] += wv * h_prev[b * HH + k];
  }
#pragma unroll
  for (int b = 0; b < 16; b++) {
#pragma unroll
    for (int off = 32; off >= 1; off >>= 1) acc[b] += __shfl_xor(acc[b], off);
  }
  float bias = b_lstm[j];
  float val = 0.f;
#pragma unroll
  for (int b = 0; b < 16; b++) if (lane == b) val = acc[b];
  if (lane < 16) ws[WS_GATES + (size_t)lane * (4 * HH) + j] = val + bias;
}

// ---- K2: LSTM cell -> h
__global__ void k_lstm(const float* __restrict__ c_prev, float* __restrict__ ws) {
  int g = blockIdx.x * 256 + threadIdx.x; // B*H = 8192
  int b = g >> 9, hj = g & 511;
  const float* gr = ws + WS_GATES + (size_t)b * (4 * HH);
  float gi = gr[hj], gf = gr[512 + hj], gg = gr[1024 + hj], go = gr[1536 + hj];
  float c = sigf(gf) * c_prev[g] + sigf(gi) * tanhf(gg);
  ws[WS_H + g] = sigf(go) * tanhf(c);
}

// ---- K3: out_raw = h @ W_out^T + b_out (one wave per row j<535)
__global__ void k_outproj(const float* __restrict__ W_out, const float* __restrict__ b_out,
                          float* __restrict__ ws) {
  int tid = threadIdx.x, lane = tid & 63, wave = tid >> 6;
  int j = blockIdx.x * 4 + wave;
  if (j >= COUT) return;
  float acc[16];
#pragma unroll
  for (int b = 0; b < 16; b++) acc[b] = 0.f;
#pragma unroll
  for (int s = 0; s < 8; s++) {
    int k = s * 64 + lane;
    float wv = W_out[j * HH + k];
#pragma unroll
    for (int b = 0; b < 16; b++) acc[b] += wv * ws[WS_H + (size_t)b * HH + k];
  }
#pragma unroll
  for (int b = 0; b < 16; b++) {
#pragma unroll
    for (int off = 32; off >= 1; off >>= 1) acc[b] += __shfl_xor(acc[b], off);
  }
  float bias = b_out[j];
  float val = 0.f;
#pragma unroll
  for (int b = 0; b < 16; b++) if (lane == b) val = acc[b];
  if (lane < 16) ws[WS_OUTR + (size_t)lane * COUT + j] = val + bias;
}

// ---- K4: parse controller outputs + key norms
__global__ void k_parse(float* __restrict__ ws) {
  int b = blockIdx.x, tid = threadIdx.x;
  const float* o = ws + WS_OUTR + (size_t)b * COUT;
  for (int t = tid; t < COUT; t += 256) {
    float v = o[t];
    if (t < 64)       ws[WS_TASK + b * 64 + t] = sigf(v);
    else if (t < 320) ws[WS_RKEYS + b * 256 + (t - 64)] = sigf(v);
    else if (t < 324) ws[WS_RBETA + b * 4 + (t - 320)] = oneplusf(v);
    else if (t < 328) ws[WS_FGATE + b * 4 + (t - 324)] = sigf(v);
    else if (t < 392) ws[WS_WKEY + b * 64 + (t - 328)] = sigf(v);
    else if (t == 392) ws[WS_WBETA + b] = oneplusf(v);
    else if (t < 457) ws[WS_ERASE + b * 64 + (t - 393)] = sigf(v);
    else if (t < 521) ws[WS_WVEC + b * 64 + (t - 457)] = sigf(v);
    else if (t == 521) ws[WS_AGATE + b] = sigf(v);
    else if (t == 522) ws[WS_WGATE + b] = sigf(v);
    else if (t >= 523 && ((t - 523) % 3) == 0) {
      int r = (t - 523) / 3;
      float a = o[523 + r * 3], bb = o[523 + r * 3 + 1], cc = o[523 + r * 3 + 2];
      float m = fmaxf(a, fmaxf(bb, cc));
      float ea = expf(a - m), eb = expf(bb - m), ec = expf(cc - m);
      float inv = 1.f / (ea + eb + ec);
      ws[WS_MODES + b * 12 + r * 3 + 0] = ea * inv;
      ws[WS_MODES + b * 12 + r * 3 + 1] = eb * inv;
      ws[WS_MODES + b * 12 + r * 3 + 2] = ec * inv;
    }
  }
  __syncthreads();
  if (tid < 5) {
    const float* kp = (tid < 4) ? (ws + WS_RKEYS + b * 256 + tid * 64) : (ws + WS_WKEY + b * 64);
    float s = 0.f;
    for (int m = 0; m < 64; m++) { float x = kp[m]; s += x * x; }
    ws[WS_KN + b * 5 + tid] = sqrtf(s);
  }
}

// ---- K5: content scores for 4 read keys + write key (one thread per (b,n))
__global__ void k_scores(const float* __restrict__ memory, float* __restrict__ ws) {
  __shared__ __align__(16) float kb[5][64];
  __shared__ float kn[5], beta[5];
  int tid = threadIdx.x;
  int b = blockIdx.x >> 3;
  int n = ((blockIdx.x & 7) << 8) + tid;
  kb[tid >> 6][tid & 63] = ws[WS_RKEYS + b * 256 + tid];
  if (tid < 64) kb[4][tid] = ws[WS_WKEY + b * 64 + tid];
  if (tid < 5) {
    kn[tid] = ws[WS_KN + b * 5 + tid];
    beta[tid] = (tid < 4) ? ws[WS_RBETA + b * 4 + tid] : ws[WS_WBETA + b];
  }
  __syncthreads();
  const float4* mrow = reinterpret_cast<const float4*>(memory + ((size_t)b * NN + n) * MM);
  float ss = 0.f, d[5];
#pragma unroll
  for (int k = 0; k < 5; k++) d[k] = 0.f;
#pragma unroll
  for (int i = 0; i < 16; i++) {
    float4 m = mrow[i];
    ss += m.x * m.x + m.y * m.y + m.z * m.z + m.w * m.w;
#pragma unroll
    for (int k = 0; k < 5; k++) {
      float4 kv = *reinterpret_cast<const float4*>(&kb[k][i * 4]);
      d[k] += m.x * kv.x + m.y * kv.y + m.z * kv.z + m.w * kv.w;
    }
  }
  float mn = sqrtf(ss);
#pragma unroll
  for (int k = 0; k < 5; k++) {
    float sim = d[k] / (kn[k] * mn + 1e-8f);
    ws[WS_SCORE + ((size_t)b * 5 + k) * NN + n] = beta[k] * sim;
  }
}

// ---- K6: row softmax over N for the 80 (b,key) rows
__global__ void k_softmax(float* __restrict__ ws) {
  int row = blockIdx.x; // b*5+k
  int tid = threadIdx.x, lane = tid & 63, wave = tid >> 6;
  const float* src = ws + WS_SCORE + (size_t)row * NN;
  float v[8];
#pragma unroll
  for (int e = 0; e < 8; e++) v[e] = src[tid + e * 256];
  float mx = v[0];
#pragma unroll
  for (int e = 1; e < 8; e++) mx = fmaxf(mx, v[e]);
#pragma unroll
  for (int off = 32; off >= 1; off >>= 1) mx = fmaxf(mx, __shfl_xor(mx, off));
  __shared__ float redm[4], reds[4];
  if (lane == 0) redm[wave] = mx;
  __syncthreads();
  mx = fmaxf(fmaxf(redm[0], redm[1]), fmaxf(redm[2], redm[3]));
  float s = 0.f;
#pragma unroll
  for (int e = 0; e < 8; e++) { v[e] = expf(v[e] - mx); s += v[e]; }
#pragma unroll
  for (int off = 32; off >= 1; off >>= 1) s += __shfl_xor(s, off);
  if (lane == 0) reds[wave] = s;
  __syncthreads();
  s = reds[0] + reds[1] + reds[2] + reds[3];
  float inv = 1.f / s;
  float* dst = ws + WS_CONT + (size_t)row * NN;
#pragma unroll
  for (int e = 0; e < 8; e++) dst[tid + e * 256] = v[e] * inv;
}

// ---- K7: psi + usage (usage is an output)
__global__ void k_usage(const float* __restrict__ prw, const float* __restrict__ pu,
                        const float* __restrict__ pww, const float* __restrict__ ws,
                        float* __restrict__ out) {
  int g = blockIdx.x * 256 + threadIdx.x; // B*N
  int b = g >> 11, n = g & 2047;
  float psi = 1.f;
#pragma unroll
  for (int r = 0; r < 4; r++) {
    float fg = ws[WS_FGATE + b * 4 + r];
    psi *= (1.f - fg * prw[((size_t)b * 4 + r) * NN + n]);
  }
  float a = pu[g], w = pww[g];
  out[O_USAGE + g] = (a + w - a * w) * psi;
}

// ---- K8: allocation weighting via stable bitonic sort + cumprod (one block per b)
__global__ void k_alloc(float* __restrict__ ws, const float* __restrict__ out) {
  int b = blockIdx.x, tid = threadIdx.x;
  __shared__ float sv[NN];
  __shared__ int si[NN];
  __shared__ float tp[256];
  for (int e = 0; e < 8; e++) {
    int n = tid + e * 256;
    sv[n] = out[O_USAGE + (size_t)b * NN + n];
    si[n] = n;
  }
  __syncthreads();
  for (int k = 2; k <= NN; k <<= 1) {
    for (int j = k >> 1; j > 0; j >>= 1) {
      for (int e = 0; e < 8; e++) {
        int idx = tid + e * 256;
        int l = idx ^ j;
        if (l > idx) {
          bool up = ((idx & k) == 0);
          float va = sv[idx], vb = sv[l];
          int ia = si[idx], ib = si[l];
          bool lessBA = (vb < va) || (vb == va && ib < ia);
          bool doswap = up ? lessBA : !lessBA;
          if (doswap) { sv[idx] = vb; sv[l] = va; si[idx] = ib; si[l] = ia; }
        }
      }
      __syncthreads();
    }
  }
  // exclusive cumprod over sorted values, then scatter (1-u)*excl back
  float loc[8];
  float lp = 1.f;
#pragma unroll
  for (int e = 0; e < 8; e++) { loc[e] = sv[tid * 8 + e]; lp *= loc[e]; }
  tp[tid] = lp;
  __syncthreads();
  if (tid == 0) {
    float run = 1.f;
    for (int t = 0; t < 256; t++) { float tmp = tp[t]; tp[t] = run; run *= tmp; }
  }
  __syncthreads();
  float excl = tp[tid];
#pragma unroll
  for (int e = 0; e < 8; e++) {
    float u = loc[e];
    ws[WS_ALLOC + (size_t)b * NN + si[tid * 8 + e]] = (1.f - u) * excl;
    excl *= u;
  }
}

// ---- K9: write weights
__global__ void k_writew(float* __restrict__ ws) {
  int g = blockIdx.x * 256 + threadIdx.x; // B*N
  int b = g >> 11, n = g & 2047;
  float ag = ws[WS_AGATE + b], wg = ws[WS_WGATE + b];
  float cw = ws[WS_CONT + ((size_t)b * 5 + 4) * NN + n];
  ws[WS_WW + g] = wg * (ag * ws[WS_ALLOC + g] + (1.f - ag) * cw);
}

// ---- K10: p_new = (1 - sum(ww)) * precedence + ww (one block per b)
__global__ void k_pnew(const float* __restrict__ prec, float* __restrict__ ws,
                       float* __restrict__ out) {
  int b = blockIdx.x, tid = threadIdx.x, lane = tid & 63, wave = tid >> 6;
  const float* wwr = ws + WS_WW + (size_t)b * NN;
  float v[8], s = 0.f;
#pragma unroll
  for (int e = 0; e < 8; e++) { v[e] = wwr[tid + e * 256]; s += v[e]; }
#pragma unroll
  for (int off = 32; off >= 1; off >>= 1) s += __shfl_xor(s, off);
  __shared__ float red[4];
  if (lane == 0) red[wave] = s;
  __syncthreads();
  s = red[0] + red[1] + red[2] + red[3];
  float om = 1.f - s;
#pragma unroll
  for (int e = 0; e < 8; e++) {
    int n = tid + e * 256;
    out[O_PNEW + (size_t)b * NN + n] = om * prec[(size_t)b * NN + n] + v[e];
  }
}

// ---- K11: memory_new (elementwise)
__global__ void k_memnew(const float* __restrict__ mem, const float* __restrict__ ws,
                         float* __restrict__ out) {
  size_t g = (size_t)blockIdx.x * 256 + threadIdx.x; // B*N*M
  int b = (int)(g >> 17);
  int m = (int)(g & 63);
  float wwv = ws[WS_WW + (g >> 6)];
  float ev = ws[WS_ERASE + b * 64 + m], wv = ws[WS_WVEC + b * 64 + m];
  out[O_MEM + g] = mem[g] * (1.f - wwv * ev) + wwv * wv;
}

// ---- K12: the fused streaming pass over L: fwd_w, bwd_w partials, link_new
__global__ void __launch_bounds__(256) k_link(const float* __restrict__ L,
                                              const float* __restrict__ wprev,
                                              float* __restrict__ ws, float* __restrict__ out) {
  int b = blockIdx.y, chunk = blockIdx.x;
  int i0 = chunk * ROWS;
  int tid = threadIdx.x, lane = tid & 63, wave = tid >> 6;
  __shared__ float wwrow[ROWS];
  __shared__ float wprow[4][ROWS];
  __shared__ float fpart[4][4][ROWS]; // [wave][r][ii]
  if (tid < ROWS) wwrow[tid] = ws[WS_WW + (size_t)b * NN + i0 + tid];
  { int r = tid >> 6, ii = tid & 63;
    wprow[r][ii] = wprev[((size_t)b * 4 + r) * NN + i0 + ii]; }
  // per-thread fixed columns: j = s*1024 + tid*4, s=0,1
  float4 wp[2][4], pn[2], wwj[2];
#pragma unroll
  for (int s = 0; s < 2; s++) {
    int j = s * 1024 + tid * 4;
#pragma unroll
    for (int r = 0; r < 4; r++)
      wp[s][r] = *reinterpret_cast<const float4*>(&wprev[((size_t)b * 4 + r) * NN + j]);
    pn[s] = *reinterpret_cast<const float4*>(&out[O_PNEW + (size_t)b * NN + j]);
    wwj[s] = *reinterpret_cast<const float4*>(&ws[WS_WW + (size_t)b * NN + j]);
  }
  __syncthreads();
  float4 bacc[2][4];
#pragma unroll
  for (int s = 0; s < 2; s++)
#pragma unroll
    for (int r = 0; r < 4; r++) { bacc[s][r].x = 0; bacc[s][r].y = 0; bacc[s][r].z = 0; bacc[s][r].w = 0; }
  const float* Lb = L + (size_t)b * NN * NN;
  float* linkb = out + O_LINK + (size_t)b * NN * NN;
  for (int ii = 0; ii < ROWS; ii++) {
    int i = i0 + ii;
    const float4* lr = reinterpret_cast<const float4*>(Lb + (size_t)i * NN);
    float4 v0 = lr[tid], v1 = lr[256 + tid];
    // fwd: per-row dot with wprev rows
    float f[4];
#pragma unroll
    for (int r = 0; r < 4; r++) {
      f[r] = v0.x * wp[0][r].x + v0.y * wp[0][r].y + v0.z * wp[0][r].z + v0.w * wp[0][r].w
           + v1.x * wp[1][r].x + v1.y * wp[1][r].y + v1.z * wp[1][r].z + v1.w * wp[1][r].w;
#pragma unroll
      for (int off = 32; off >= 1; off >>= 1) f[r] += __shfl_xor(f[r], off);
    }
    if (lane == 0) {
      fpart[wave][0][ii] = f[0]; fpart[wave][1][ii] = f[1];
      fpart[wave][2][ii] = f[2]; fpart[wave][3][ii] = f[3];
    }
    // bwd: column accumulation into registers
#pragma unroll
    for (int r = 0; r < 4; r++) {
      float w = wprow[r][ii];
      bacc[0][r].x += w * v0.x; bacc[0][r].y += w * v0.y; bacc[0][r].z += w * v0.z; bacc[0][r].w += w * v0.w;
      bacc[1][r].x += w * v1.x; bacc[1][r].y += w * v1.y; bacc[1][r].z += w * v1.z; bacc[1][r].w += w * v1.w;
    }
    // link update
    float wwi = wwrow[ii];
    float4 o0, o1;
    o0.x = (1.f - wwi - wwj[0].x) * v0.x + wwi * pn[0].x;
    o0.y = (1.f - wwi - wwj[0].y) * v0.y + wwi * pn[0].y;
    o0.z = (1.f - wwi - wwj[0].z) * v0.z + wwi * pn[0].z;
    o0.w = (1.f - wwi - wwj[0].w) * v0.w + wwi * pn[0].w;
    o1.x = (1.f - wwi - wwj[1].x) * v1.x + wwi * pn[1].x;
    o1.y = (1.f - wwi - wwj[1].y) * v1.y + wwi * pn[1].y;
    o1.z = (1.f - wwi - wwj[1].z) * v1.z + wwi * pn[1].z;
    o1.w = (1.f - wwi - wwj[1].w) * v1.w + wwi * pn[1].w;
    int j0 = tid * 4, j1 = 1024 + tid * 4;
    if (i == j0) o0.x = 0.f; if (i == j0 + 1) o0.y = 0.f;
    if (i == j0 + 2) o0.z = 0.f; if (i == j0 + 3) o0.w = 0.f;
    if (i == j1) o1.x = 0.f; if (i == j1 + 1) o1.y = 0.f;
    if (i == j1 + 2) o1.z = 0.f; if (i == j1 + 3) o1.w = 0.f;
    float4* orow = reinterpret_cast<float4*>(linkb + (size_t)i * NN);
    orow[tid] = o0; orow[256 + tid] = o1;
  }
  __syncthreads();
  { int r = tid >> 6, ii = tid & 63;
    float s = fpart[0][r][ii] + fpart[1][r][ii] + fpart[2][r][ii] + fpart[3][r][ii];
    ws[WS_FWD + ((size_t)b * 4 + r) * NN + i0 + ii] = s; }
#pragma unroll
  for (int s = 0; s < 2; s++)
#pragma unroll
    for (int r = 0; r < 4; r++)
      *reinterpret_cast<float4*>(
          &ws[WS_BPART + (((size_t)b * CHUNKS + chunk) * 4 + r) * NN + s * 1024 + tid * 4]) = bacc[s][r];
}

// ---- K13: reduce bwd partials over chunks (fixed order => deterministic)
__global__ void k_bwdred(float* __restrict__ ws) {
  int g = blockIdx.x * 256 + threadIdx.x; // B*4*N
  int b = g >> 13, rn = g & 8191;
  float s = 0.f;
  for (int c = 0; c < CHUNKS; c++)
    s += ws[WS_BPART + ((size_t)b * CHUNKS + c) * 8192 + rn];
  ws[WS_BWD + g] = s;
}

// ---- K14: read weights combine (output)
__global__ void k_readw(float* __restrict__ ws, float* __restrict__ out) {
  int g = blockIdx.x * 256 + threadIdx.x; // B*4*N
  int b = g >> 13, rn = g & 8191, r = rn >> 11, n = rn & 2047;
  float m0 = ws[WS_MODES + b * 12 + r * 3 + 0];
  float m1 = ws[WS_MODES + b * 12 + r * 3 + 1];
  float m2 = ws[WS_MODES + b * 12 + r * 3 + 2];
  float rw = m0 * ws[WS_BWD + g] + m1 * ws[WS_CONT + ((size_t)b * 5 + r) * NN + n] + m2 * ws[WS_FWD + g];
  out[O_READW + g] = rw;
}

// ---- K15: reads = read_w @ memory (one block per b)
__global__ void k_reads(const float* __restrict__ memory, const float* __restrict__ out,
                        float* __restrict__ ws) {
  int b = blockIdx.x, tid = threadIdx.x;
  int m = tid & 63, grp = tid >> 6;
  float acc[4] = {0.f, 0.f, 0.f, 0.f};
  for (int n = grp * 512; n < grp * 512 + 512; n++) {
    float mv = memory[((size_t)b * NN + n) * MM + m];
#pragma unroll
    for (int r = 0; r < 4; r++)
      acc[r] += out[O_READW + ((size_t)b * 4 + r) * NN + n] * mv;
  }
  __shared__ float part[4][4][64];
#pragma unroll
  for (int r = 0; r < 4; r++) part[grp][r][m] = acc[r];
  __syncthreads();
  { int r = tid >> 6, mm = tid & 63;
    float s = part[0][r][mm] + part[1][r][mm] + part[2][r][mm] + part[3][r][mm];
    ws[WS_READS + (size_t)b * 256 + r * 64 + mm] = s; }
}

// ---- K16: read projection + final output
__global__ void k_final(const float* __restrict__ W_read, const float* __restrict__ b_read,
                        const float* __restrict__ ws, float* __restrict__ out) {
  int g = blockIdx.x * 256 + threadIdx.x; // B*64
  int b = g >> 6, o = g & 63;
  float acc = b_read[o];
  for (int k = 0; k < 256; k++) acc += W_read[o * 256 + k] * ws[WS_READS + (size_t)b * 256 + k];
  float ro = sigf(acc);
  out[O_OUT + g] = sigf(ro + ws[WS_TASK + g]);
}

extern "C" void kernel_launch(void* const* d_in, const int* in_sizes, int n_in,
                              void* d_out, int out_size, void* d_ws, size_t ws_size,
                              hipStream_t stream) {
  (void)in_sizes; (void)n_in; (void)out_size; (void)ws_size; // WS_TOTAL*4 ≈ 19.7 MB needed
  const float* task   = (const float*)d_in[0];
  const float* memory = (const float*)d_in[1];
  const float* links  = (const float*)d_in[2];
  const float* preads = (const float*)d_in[3];
  const float* prw    = (const float*)d_in[4];
  const float* pusage = (const float*)d_in[5];
  const float* pww    = (const float*)d_in[6];
  const float* prec   = (const float*)d_in[7];
  const float* h_prev = (const float*)d_in[8];
  const float* c_prev = (const float*)d_in[9];
  const float* W_ih   = (const float*)d_in[10];
  const float* W_hh   = (const float*)d_in[11];
  const float* b_lstm = (const float*)d_in[12];
  const float* W_out  = (const float*)d_in[13];
  const float* b_out  = (const float*)d_in[14];
  const float* W_read = (const float*)d_in[15];
  const float* b_read = (const float*)d_in[16];
  float* out = (float*)d_out;
  float* ws  = (float*)d_ws;

  k_gates<<<512, 256, 0, stream>>>(task, preads, h_prev, W_ih, W_hh, b_lstm, ws);
  k_lstm<<<32, 256, 0, stream>>>(c_prev, ws);
  k_outproj<<<134, 256, 0, stream>>>(W_out, b_out, ws);
  k_parse<<<16, 256, 0, stream>>>(ws);
  k_scores<<<128, 256, 0, stream>>>(memory, ws);
  k_softmax<<<80, 256, 0, stream>>>(ws);
  k_usage<<<128, 256, 0, stream>>>(prw, pusage, pww, ws, out);
  k_alloc<<<16, 256, 0, stream>>>(ws, out);
  k_writew<<<128, 256, 0, stream>>>(ws);
  k_pnew<<<16, 256, 0, stream>>>(prec, ws, out);
  k_memnew<<<8192, 256, 0, stream>>>(memory, ws, out);
  k_link<<<dim3(CHUNKS, BB), 256, 0, stream>>>(links, prw, ws, out);
  k_bwdred<<<512, 256, 0, stream>>>(ws);
  k_readw<<<512, 256, 0, stream>>>(ws, out);
  k_reads<<<16, 256, 0, stream>>>(memory, out, ws);
  k_final<<<4, 256, 0, stream>>>(W_read, b_read, ws, out);
}

// Round 2
// 303.829 us; speedup vs baseline: 1.0308x; 1.0308x over previous
//
#include <hip/hip_runtime.h>
#include <math.h>

// DNC single step, MI355X. All f32. B=16,N=2048,M=64,R=4,H=512.
constexpr int BB = 16, NN = 2048, MM = 64, RR = 4, HH = 512;
constexpr int CIN = 320, COUT = 535;
constexpr int CHUNKS = 32, ROWS = 64; // link kernel row-chunking

// ---- output layout (floats): output, memory_new, link_new, p_new, usage, read_w
constexpr size_t O_OUT   = 0;
constexpr size_t O_MEM   = O_OUT + (size_t)BB * 64;
constexpr size_t O_LINK  = O_MEM + (size_t)BB * NN * MM;
constexpr size_t O_PNEW  = O_LINK + (size_t)BB * NN * NN;
constexpr size_t O_USAGE = O_PNEW + (size_t)BB * NN;
constexpr size_t O_READW = O_USAGE + (size_t)BB * NN;

// ---- workspace layout (floats)
constexpr size_t WS_GATES = 0;                                   // B*2048
constexpr size_t WS_H     = WS_GATES + (size_t)BB * 4 * HH;      // B*512
constexpr size_t WS_OUTR  = WS_H + (size_t)BB * HH;              // B*535 (raw, for modes)
constexpr size_t WS_TASK  = WS_OUTR + (size_t)BB * COUT;         // B*64
constexpr size_t WS_RKEYS = WS_TASK + (size_t)BB * 64;           // B*256
constexpr size_t WS_RBETA = WS_RKEYS + (size_t)BB * 256;         // B*4
constexpr size_t WS_FGATE = WS_RBETA + (size_t)BB * 4;           // B*4
constexpr size_t WS_WKEY  = WS_FGATE + (size_t)BB * 4;           // B*64
constexpr size_t WS_WBETA = WS_WKEY + (size_t)BB * 64;           // B
constexpr size_t WS_ERASE = WS_WBETA + (size_t)BB;               // B*64
constexpr size_t WS_WVEC  = WS_ERASE + (size_t)BB * 64;          // B*64
constexpr size_t WS_AGATE = WS_WVEC + (size_t)BB * 64;           // B
constexpr size_t WS_WGATE = WS_AGATE + (size_t)BB;               // B
constexpr size_t WS_CONT  = WS_WGATE + (size_t)BB;               // B*5*N
constexpr size_t WS_WW    = WS_CONT + (size_t)BB * 5 * NN;       // B*N
constexpr size_t WS_FWD   = WS_WW + (size_t)BB * NN;             // B*4*N
constexpr size_t WS_BPART = WS_FWD + (size_t)BB * 4 * NN;        // B*CHUNKS*4*N
constexpr size_t WS_RPART = WS_BPART + (size_t)BB * CHUNKS * 4 * NN; // B*8*256
constexpr size_t WS_TOTAL = WS_RPART + (size_t)BB * 8 * 256;

__device__ __forceinline__ float sigf(float x) { return 1.0f / (1.0f + expf(-x)); }
__device__ __forceinline__ float oneplusf(float x) {
  return 1.0f + fmaxf(x, 0.0f) + log1pf(expf(-fabsf(x)));
}

// ---- K1: gates = x @ W_ih^T + h_prev @ W_hh^T + b_lstm  (one wave per row j)
__global__ void k_gates(const float* __restrict__ task, const float* __restrict__ prev_reads,
                        const float* __restrict__ h_prev, const float* __restrict__ W_ih,
                        const float* __restrict__ W_hh, const float* __restrict__ b_lstm,
                        float* __restrict__ ws) {
  int tid = threadIdx.x, lane = tid & 63, wave = tid >> 6;
  int j = blockIdx.x * 4 + wave; // 0..2047
  float acc[16];
#pragma unroll
  for (int b = 0; b < 16; b++) acc[b] = 0.f;
#pragma unroll
  for (int s = 0; s < 5; s++) {
    int k = s * 64 + lane;
    float wv = W_ih[j * CIN + k];
    if (s == 0) {
#pragma unroll
      for (int b = 0; b < 16; b++) acc[b] += wv * task[b * 64 + k];
    } else {
#pragma unroll
      for (int b = 0; b < 16; b++) acc[b] += wv * prev_reads[b * 256 + (k - 64)];
    }
  }
#pragma unroll
  for (int s = 0; s < 8; s++) {
    int k = s * 64 + lane;
    float wv = W_hh[j * HH + k];
#pragma unroll
    for (int b = 0; b < 16; b++) acc[b] += wv * h_prev[b * HH + k];
  }
#pragma unroll
  for (int b = 0; b < 16; b++) {
#pragma unroll
    for (int off = 32; off >= 1; off >>= 1) acc[b] += __shfl_xor(acc[b], off);
  }
  float bias = b_lstm[j];
  float val = 0.f;
#pragma unroll
  for (int b = 0; b < 16; b++) if (lane == b) val = acc[b];
  if (lane < 16) ws[WS_GATES + (size_t)lane * (4 * HH) + j] = val + bias;
}

// ---- K2: LSTM cell -> h
__global__ void k_lstm(const float* __restrict__ c_prev, float* __restrict__ ws) {
  int g = blockIdx.x * 256 + threadIdx.x; // B*H = 8192
  int b = g >> 9, hj = g & 511;
  const float* gr = ws + WS_GATES + (size_t)b * (4 * HH);
  float gi = gr[hj], gf = gr[512 + hj], gg = gr[1024 + hj], go = gr[1536 + hj];
  float c = sigf(gf) * c_prev[g] + sigf(gi) * tanhf(gg);
  ws[WS_H + g] = sigf(go) * tanhf(c);
}

// ---- K3: out_raw = h @ W_out^T + b_out, fused parse (one wave per row j<535)
__global__ void k_outproj_parse(const float* __restrict__ W_out, const float* __restrict__ b_out,
                                float* __restrict__ ws) {
  int tid = threadIdx.x, lane = tid & 63, wave = tid >> 6;
  int j = blockIdx.x * 4 + wave;
  if (j >= COUT) return;
  float acc[16];
#pragma unroll
  for (int b = 0; b < 16; b++) acc[b] = 0.f;
#pragma unroll
  for (int s = 0; s < 8; s++) {
    int k = s * 64 + lane;
    float wv = W_out[j * HH + k];
#pragma unroll
    for (int b = 0; b < 16; b++) acc[b] += wv * ws[WS_H + (size_t)b * HH + k];
  }
#pragma unroll
  for (int b = 0; b < 16; b++) {
#pragma unroll
    for (int off = 32; off >= 1; off >>= 1) acc[b] += __shfl_xor(acc[b], off);
  }
  float bias = b_out[j];
  float val = 0.f;
#pragma unroll
  for (int b = 0; b < 16; b++) if (lane == b) val = acc[b];
  if (lane < 16) {
    int b = lane;
    float v = val + bias;
    ws[WS_OUTR + (size_t)b * COUT + j] = v; // raw kept for read-mode softmax
    if (j < 64)       ws[WS_TASK + b * 64 + j] = sigf(v);
    else if (j < 320) ws[WS_RKEYS + b * 256 + (j - 64)] = sigf(v);
    else if (j < 324) ws[WS_RBETA + b * 4 + (j - 320)] = oneplusf(v);
    else if (j < 328) ws[WS_FGATE + b * 4 + (j - 324)] = sigf(v);
    else if (j < 392) ws[WS_WKEY + b * 64 + (j - 328)] = sigf(v);
    else if (j == 392) ws[WS_WBETA + b] = oneplusf(v);
    else if (j < 457) ws[WS_ERASE + b * 64 + (j - 393)] = sigf(v);
    else if (j < 521) ws[WS_WVEC + b * 64 + (j - 457)] = sigf(v);
    else if (j == 521) ws[WS_AGATE + b] = sigf(v);
    else if (j == 522) ws[WS_WGATE + b] = sigf(v);
  }
}

// ---- K4: content scores + softmax, one block per (b,key) (fused)
__global__ void __launch_bounds__(1024) k_content(const float* __restrict__ memory,
                                                  float* __restrict__ ws) {
  int bk = blockIdx.x; // b*5+k
  int b = bk / 5, k = bk % 5;
  int t = threadIdx.x, lane = t & 63, wave = t >> 6;
  __shared__ __align__(16) float kb[64];
  __shared__ float sc[NN];
  __shared__ float red[16];
  __shared__ float skn, sbeta;
  if (t < 64) kb[t] = (k < 4) ? ws[WS_RKEYS + b * 256 + k * 64 + t] : ws[WS_WKEY + b * 64 + t];
  if (t == 64) sbeta = (k < 4) ? ws[WS_RBETA + b * 4 + k] : ws[WS_WBETA + b];
  __syncthreads();
  if (wave == 0) {
    float kv = kb[lane];
    float ss = kv * kv;
#pragma unroll
    for (int off = 32; off >= 1; off >>= 1) ss += __shfl_xor(ss, off);
    if (lane == 0) skn = sqrtf(ss);
  }
  __syncthreads();
  float kn = skn, beta = sbeta;
  int r = lane >> 4, c = lane & 15;
  float4 key4 = *reinterpret_cast<const float4*>(&kb[c * 4]);
  // wave handles 128 rows, 4 per iteration (16 lanes per row)
  for (int i = 0; i < 32; i++) {
    int n = wave * 128 + i * 4 + r;
    float4 v = *reinterpret_cast<const float4*>(&memory[((size_t)b * NN + n) * MM + c * 4]);
    float d = v.x * key4.x + v.y * key4.y + v.z * key4.z + v.w * key4.w;
    float s2 = v.x * v.x + v.y * v.y + v.z * v.z + v.w * v.w;
#pragma unroll
    for (int off = 1; off <= 8; off <<= 1) {
      d += __shfl_xor(d, off);
      s2 += __shfl_xor(s2, off);
    }
    if (c == 0) sc[n] = beta * d / (kn * sqrtf(s2) + 1e-8f);
  }
  __syncthreads();
  float v0 = sc[t], v1 = sc[t + 1024];
  float mx = fmaxf(v0, v1);
#pragma unroll
  for (int off = 32; off >= 1; off >>= 1) mx = fmaxf(mx, __shfl_xor(mx, off));
  if (lane == 0) red[wave] = mx;
  __syncthreads();
  mx = red[0];
  for (int w2 = 1; w2 < 16; w2++) mx = fmaxf(mx, red[w2]);
  float e0 = expf(v0 - mx), e1 = expf(v1 - mx);
  float s = e0 + e1;
#pragma unroll
  for (int off = 32; off >= 1; off >>= 1) s += __shfl_xor(s, off);
  __syncthreads(); // red reuse
  if (lane == 0) red[wave] = s;
  __syncthreads();
  s = 0.f;
  for (int w2 = 0; w2 < 16; w2++) s += red[w2];
  float inv = 1.f / s;
  float* dst = ws + WS_CONT + (size_t)bk * NN;
  dst[t] = e0 * inv;
  dst[t + 1024] = e1 * inv;
}

// ---- K5: usage + allocation (bitonic sort) + write weights + p_new, one block per b
__global__ void __launch_bounds__(1024) k_write_path(
    const float* __restrict__ prw, const float* __restrict__ pu,
    const float* __restrict__ pww, const float* __restrict__ prec,
    float* __restrict__ ws, float* __restrict__ out) {
  int b = blockIdx.x, t = threadIdx.x, lane = t & 63, wave = t >> 6;
  __shared__ float sv[NN];
  __shared__ int si[NN];
  __shared__ float al[NN];
  __shared__ float wred[16];
  float fg[4];
#pragma unroll
  for (int r = 0; r < 4; r++) fg[r] = ws[WS_FGATE + b * 4 + r];
#pragma unroll
  for (int e = 0; e < 2; e++) {
    int n = t + e * 1024;
    float psi = 1.f;
#pragma unroll
    for (int r = 0; r < 4; r++) psi *= (1.f - fg[r] * prw[((size_t)b * 4 + r) * NN + n]);
    float a = pu[(size_t)b * NN + n], w = pww[(size_t)b * NN + n];
    float u = (a + w - a * w) * psi;
    out[O_USAGE + (size_t)b * NN + n] = u;
    sv[n] = u;
    si[n] = n;
  }
  __syncthreads();
  // stable bitonic sort ascending (value, index)
  for (int k = 2; k <= NN; k <<= 1) {
    for (int j = k >> 1; j > 0; j >>= 1) {
#pragma unroll
      for (int e = 0; e < 2; e++) {
        int idx = t + e * 1024;
        int l = idx ^ j;
        if (l > idx) {
          bool up = ((idx & k) == 0);
          float va = sv[idx], vb = sv[l];
          int ia = si[idx], ib = si[l];
          bool lessBA = (vb < va) || (vb == va && ib < ia);
          if (up ? lessBA : !lessBA) { sv[idx] = vb; sv[l] = va; si[idx] = ib; si[l] = ia; }
        }
      }
      __syncthreads();
    }
  }
  // exclusive cumprod over sorted values (thread owns sorted elems 2t, 2t+1)
  float u0 = sv[2 * t], u1 = sv[2 * t + 1];
  int i0 = si[2 * t], i1 = si[2 * t + 1];
  float lp = u0 * u1;
  float x = lp;
#pragma unroll
  for (int off = 1; off < 64; off <<= 1) {
    float y = __shfl_up(x, off);
    if (lane >= off) x *= y;
  }
  if (lane == 63) wred[wave] = x;
  float ex = __shfl_up(x, 1);
  if (lane == 0) ex = 1.f;
  __syncthreads();
  float base = 1.f;
  for (int w2 = 0; w2 < wave; w2++) base *= wred[w2];
  float E = base * ex;
  al[i0] = (1.f - u0) * E;
  E *= u0;
  al[i1] = (1.f - u1) * E;
  __syncthreads();
  float ag = ws[WS_AGATE + b], wg = ws[WS_WGATE + b];
  float wwv[2], ssum = 0.f;
#pragma unroll
  for (int e = 0; e < 2; e++) {
    int n = t + e * 1024;
    float cw = ws[WS_CONT + ((size_t)b * 5 + 4) * NN + n];
    wwv[e] = wg * (ag * al[n] + (1.f - ag) * cw);
    ws[WS_WW + (size_t)b * NN + n] = wwv[e];
    ssum += wwv[e];
  }
#pragma unroll
  for (int off = 32; off >= 1; off >>= 1) ssum += __shfl_xor(ssum, off);
  __syncthreads(); // wred reuse
  if (lane == 0) wred[wave] = ssum;
  __syncthreads();
  float tot = 0.f;
  for (int w2 = 0; w2 < 16; w2++) tot += wred[w2];
  float om = 1.f - tot;
#pragma unroll
  for (int e = 0; e < 2; e++) {
    int n = t + e * 1024;
    out[O_PNEW + (size_t)b * NN + n] = om * prec[(size_t)b * NN + n] + wwv[e];
  }
}

// ---- K6: memory_new (elementwise)
__global__ void k_memnew(const float* __restrict__ mem, const float* __restrict__ ws,
                         float* __restrict__ out) {
  size_t g = (size_t)blockIdx.x * 256 + threadIdx.x; // B*N*M
  int b = (int)(g >> 17);
  int m = (int)(g & 63);
  float wwv = ws[WS_WW + (g >> 6)];
  float ev = ws[WS_ERASE + b * 64 + m], wv = ws[WS_WVEC + b * 64 + m];
  out[O_MEM + g] = mem[g] * (1.f - wwv * ev) + wwv * wv;
}

// ---- K7: the fused streaming pass over L: fwd_w, bwd_w partials, link_new
__global__ void __launch_bounds__(256) k_link(const float* __restrict__ L,
                                              const float* __restrict__ wprev,
                                              float* __restrict__ ws, float* __restrict__ out) {
  int b = blockIdx.y, chunk = blockIdx.x;
  int i0 = chunk * ROWS;
  int tid = threadIdx.x, lane = tid & 63, wave = tid >> 6;
  __shared__ float wwrow[ROWS];
  __shared__ float wprow[4][ROWS];
  __shared__ float fpart[4][4][ROWS]; // [wave][r][ii]
  if (tid < ROWS) wwrow[tid] = ws[WS_WW + (size_t)b * NN + i0 + tid];
  { int r = tid >> 6, ii = tid & 63;
    wprow[r][ii] = wprev[((size_t)b * 4 + r) * NN + i0 + ii]; }
  float4 wp[2][4], pn[2], wwj[2];
#pragma unroll
  for (int s = 0; s < 2; s++) {
    int j = s * 1024 + tid * 4;
#pragma unroll
    for (int r = 0; r < 4; r++)
      wp[s][r] = *reinterpret_cast<const float4*>(&wprev[((size_t)b * 4 + r) * NN + j]);
    pn[s] = *reinterpret_cast<const float4*>(&out[O_PNEW + (size_t)b * NN + j]);
    wwj[s] = *reinterpret_cast<const float4*>(&ws[WS_WW + (size_t)b * NN + j]);
  }
  __syncthreads();
  float4 bacc[2][4];
#pragma unroll
  for (int s = 0; s < 2; s++)
#pragma unroll
    for (int r = 0; r < 4; r++) { bacc[s][r].x = 0; bacc[s][r].y = 0; bacc[s][r].z = 0; bacc[s][r].w = 0; }
  const float* Lb = L + (size_t)b * NN * NN;
  float* linkb = out + O_LINK + (size_t)b * NN * NN;
  for (int ii = 0; ii < ROWS; ii++) {
    int i = i0 + ii;
    const float4* lr = reinterpret_cast<const float4*>(Lb + (size_t)i * NN);
    float4 v0 = lr[tid], v1 = lr[256 + tid];
    float f[4];
#pragma unroll
    for (int r = 0; r < 4; r++) {
      f[r] = v0.x * wp[0][r].x + v0.y * wp[0][r].y + v0.z * wp[0][r].z + v0.w * wp[0][r].w
           + v1.x * wp[1][r].x + v1.y * wp[1][r].y + v1.z * wp[1][r].z + v1.w * wp[1][r].w;
#pragma unroll
      for (int off = 32; off >= 1; off >>= 1) f[r] += __shfl_xor(f[r], off);
    }
    if (lane == 0) {
      fpart[wave][0][ii] = f[0]; fpart[wave][1][ii] = f[1];
      fpart[wave][2][ii] = f[2]; fpart[wave][3][ii] = f[3];
    }
#pragma unroll
    for (int r = 0; r < 4; r++) {
      float w = wprow[r][ii];
      bacc[0][r].x += w * v0.x; bacc[0][r].y += w * v0.y; bacc[0][r].z += w * v0.z; bacc[0][r].w += w * v0.w;
      bacc[1][r].x += w * v1.x; bacc[1][r].y += w * v1.y; bacc[1][r].z += w * v1.z; bacc[1][r].w += w * v1.w;
    }
    float wwi = wwrow[ii];
    float4 o0, o1;
    o0.x = (1.f - wwi - wwj[0].x) * v0.x + wwi * pn[0].x;
    o0.y = (1.f - wwi - wwj[0].y) * v0.y + wwi * pn[0].y;
    o0.z = (1.f - wwi - wwj[0].z) * v0.z + wwi * pn[0].z;
    o0.w = (1.f - wwi - wwj[0].w) * v0.w + wwi * pn[0].w;
    o1.x = (1.f - wwi - wwj[1].x) * v1.x + wwi * pn[1].x;
    o1.y = (1.f - wwi - wwj[1].y) * v1.y + wwi * pn[1].y;
    o1.z = (1.f - wwi - wwj[1].z) * v1.z + wwi * pn[1].z;
    o1.w = (1.f - wwi - wwj[1].w) * v1.w + wwi * pn[1].w;
    int j0 = tid * 4, j1 = 1024 + tid * 4;
    if (i == j0) o0.x = 0.f; if (i == j0 + 1) o0.y = 0.f;
    if (i == j0 + 2) o0.z = 0.f; if (i == j0 + 3) o0.w = 0.f;
    if (i == j1) o1.x = 0.f; if (i == j1 + 1) o1.y = 0.f;
    if (i == j1 + 2) o1.z = 0.f; if (i == j1 + 3) o1.w = 0.f;
    float4* orow = reinterpret_cast<float4*>(linkb + (size_t)i * NN);
    orow[tid] = o0; orow[256 + tid] = o1;
  }
  __syncthreads();
  { int r = tid >> 6, ii = tid & 63;
    float s = fpart[0][r][ii] + fpart[1][r][ii] + fpart[2][r][ii] + fpart[3][r][ii];
    ws[WS_FWD + ((size_t)b * 4 + r) * NN + i0 + ii] = s; }
#pragma unroll
  for (int s = 0; s < 2; s++)
#pragma unroll
    for (int r = 0; r < 4; r++)
      *reinterpret_cast<float4*>(
          &ws[WS_BPART + (((size_t)b * CHUNKS + chunk) * 4 + r) * NN + s * 1024 + tid * 4]) = bacc[s][r];
}

// ---- K8: bwd chunk-reduce + read modes + read_w + read partial dots (fused)
__global__ void __launch_bounds__(256) k_readrw(const float* __restrict__ memory,
                                                float* __restrict__ ws, float* __restrict__ out) {
  int b = blockIdx.x >> 3, chunk = blockIdx.x & 7;
  int n0 = chunk * 256;
  int t = threadIdx.x, lane = t & 63, wave = t >> 6;
  __shared__ float fm[4][3];
  __shared__ float rwl[4][256];
  __shared__ float part[4][4][64];
  if (t < 4) {
    const float* o = ws + WS_OUTR + (size_t)b * COUT + 523 + t * 3;
    float a = o[0], bb = o[1], cc = o[2];
    float m = fmaxf(a, fmaxf(bb, cc));
    float ea = expf(a - m), eb = expf(bb - m), ec = expf(cc - m);
    float iv = 1.f / (ea + eb + ec);
    fm[t][0] = ea * iv; fm[t][1] = eb * iv; fm[t][2] = ec * iv;
  }
  __syncthreads();
#pragma unroll
  for (int r = 0; r < 4; r++) {
    int n = n0 + t;
    float bwd = 0.f;
    for (int c2 = 0; c2 < CHUNKS; c2++)
      bwd += ws[WS_BPART + (((size_t)b * CHUNKS + c2) * 4 + r) * NN + n];
    float fwd = ws[WS_FWD + ((size_t)b * 4 + r) * NN + n];
    float cont = ws[WS_CONT + ((size_t)b * 5 + r) * NN + n];
    float rw = fm[r][0] * bwd + fm[r][1] * cont + fm[r][2] * fwd;
    out[O_READW + ((size_t)b * 4 + r) * NN + n] = rw;
    rwl[r][t] = rw;
  }
  __syncthreads();
  float acc[4] = {0.f, 0.f, 0.f, 0.f};
  for (int ii = 0; ii < 64; ii++) {
    int nl = wave * 64 + ii;
    float mv = memory[((size_t)b * NN + n0 + nl) * MM + lane];
#pragma unroll
    for (int r = 0; r < 4; r++) acc[r] += rwl[r][nl] * mv;
  }
#pragma unroll
  for (int r = 0; r < 4; r++) part[wave][r][lane] = acc[r];
  __syncthreads();
  { int r = t >> 6, m = t & 63;
    float s = part[0][r][m] + part[1][r][m] + part[2][r][m] + part[3][r][m];
    ws[WS_RPART + ((size_t)(b * 8 + chunk)) * 256 + t] = s; }
}

// ---- K9: reduce read partials + read projection + final output
__global__ void k_final(const float* __restrict__ W_read, const float* __restrict__ b_read,
                        const float* __restrict__ ws, float* __restrict__ out) {
  int b = blockIdx.x, t = threadIdx.x, lane = t & 63, wave = t >> 6;
  __shared__ float rds[256];
  float s = 0.f;
  for (int c = 0; c < 8; c++) s += ws[WS_RPART + ((size_t)(b * 8 + c)) * 256 + t];
  rds[t] = s;
  __syncthreads();
  for (int oi = 0; oi < 16; oi++) {
    int o = wave * 16 + oi;
    float acc = 0.f;
#pragma unroll
    for (int s2 = 0; s2 < 4; s2++) {
      int kk = s2 * 64 + lane;
      acc += W_read[o * 256 + kk] * rds[kk];
    }
#pragma unroll
    for (int off = 32; off >= 1; off >>= 1) acc += __shfl_xor(acc, off);
    if (lane == 0) {
      float ro = sigf(acc + b_read[o]);
      out[O_OUT + b * 64 + o] = sigf(ro + ws[WS_TASK + b * 64 + o]);
    }
  }
}

extern "C" void kernel_launch(void* const* d_in, const int* in_sizes, int n_in,
                              void* d_out, int out_size, void* d_ws, size_t ws_size,
                              hipStream_t stream) {
  (void)in_sizes; (void)n_in; (void)out_size; (void)ws_size;
  const float* task   = (const float*)d_in[0];
  const float* memory = (const float*)d_in[1];
  const float* links  = (const float*)d_in[2];
  const float* preads = (const float*)d_in[3];
  const float* prw    = (const float*)d_in[4];
  const float* pusage = (const float*)d_in[5];
  const float* pww    = (const float*)d_in[6];
  const float* prec   = (const float*)d_in[7];
  const float* h_prev = (const float*)d_in[8];
  const float* c_prev = (const float*)d_in[9];
  const float* W_ih   = (const float*)d_in[10];
  const float* W_hh   = (const float*)d_in[11];
  const float* b_lstm = (const float*)d_in[12];
  const float* W_out  = (const float*)d_in[13];
  const float* b_out  = (const float*)d_in[14];
  const float* W_read = (const float*)d_in[15];
  const float* b_read = (const float*)d_in[16];
  float* out = (float*)d_out;
  float* ws  = (float*)d_ws;

  k_gates<<<512, 256, 0, stream>>>(task, preads, h_prev, W_ih, W_hh, b_lstm, ws);
  k_lstm<<<32, 256, 0, stream>>>(c_prev, ws);
  k_outproj_parse<<<134, 256, 0, stream>>>(W_out, b_out, ws);
  k_content<<<80, 1024, 0, stream>>>(memory, ws);
  k_write_path<<<16, 1024, 0, stream>>>(prw, pusage, pww, prec, ws, out);
  k_memnew<<<8192, 256, 0, stream>>>(memory, ws, out);
  k_link<<<dim3(CHUNKS, BB), 256, 0, stream>>>(links, prw, ws, out);
  k_readrw<<<128, 256, 0, stream>>>(memory, ws, out);
  k_final<<<16, 256, 0, stream>>>(W_read, b_read, ws, out);
}

// Round 3
// 238.839 us; speedup vs baseline: 1.3113x; 1.2721x over previous
//
#include <hip/hip_runtime.h>
#include <math.h>

// DNC single step, MI355X. All f32. B=16,N=2048,M=64,R=4,H=512.
constexpr int BB = 16, NN = 2048, MM = 64, RR = 4, HH = 512;
constexpr int CIN = 320, COUT = 535;
constexpr int CHUNKS = 64, ROWS = 32; // link kernel row-chunking (512 thr/block)

typedef float f32x4 __attribute__((ext_vector_type(4)));

// ---- output layout (floats): output, memory_new, link_new, p_new, usage, read_w
constexpr size_t O_OUT   = 0;
constexpr size_t O_MEM   = O_OUT + (size_t)BB * 64;
constexpr size_t O_LINK  = O_MEM + (size_t)BB * NN * MM;
constexpr size_t O_PNEW  = O_LINK + (size_t)BB * NN * NN;
constexpr size_t O_USAGE = O_PNEW + (size_t)BB * NN;
constexpr size_t O_READW = O_USAGE + (size_t)BB * NN;

// ---- workspace layout (floats)
constexpr size_t WS_H     = 0;                                   // B*512
constexpr size_t WS_OUTR  = WS_H + (size_t)BB * HH;              // B*535 (raw, for modes)
constexpr size_t WS_TASK  = WS_OUTR + (size_t)BB * COUT;         // B*64
constexpr size_t WS_RKEYS = WS_TASK + (size_t)BB * 64;           // B*256
constexpr size_t WS_RBETA = WS_RKEYS + (size_t)BB * 256;         // B*4
constexpr size_t WS_FGATE = WS_RBETA + (size_t)BB * 4;           // B*4
constexpr size_t WS_WKEY  = WS_FGATE + (size_t)BB * 4;           // B*64
constexpr size_t WS_WBETA = WS_WKEY + (size_t)BB * 64;           // B
constexpr size_t WS_ERASE = WS_WBETA + (size_t)BB;               // B*64
constexpr size_t WS_WVEC  = WS_ERASE + (size_t)BB * 64;          // B*64
constexpr size_t WS_AGATE = WS_WVEC + (size_t)BB * 64;           // B
constexpr size_t WS_WGATE = WS_AGATE + (size_t)BB;               // B
constexpr size_t WS_CONT  = WS_WGATE + (size_t)BB;               // B*5*N
constexpr size_t WS_WW    = WS_CONT + (size_t)BB * 5 * NN;       // B*N
constexpr size_t WS_FWD   = WS_WW + (size_t)BB * NN;             // B*4*N
constexpr size_t WS_BPART = WS_FWD + (size_t)BB * 4 * NN;        // B*CHUNKS*4*N = 8.39M floats
constexpr size_t WS_RPART = WS_BPART + (size_t)BB * CHUNKS * 4 * NN; // B*8*256
constexpr size_t WS_TOTAL = WS_RPART + (size_t)BB * 8 * 256;     // ~9.35M floats ~37.4 MB

__device__ __forceinline__ float sigf(float x) { return 1.0f / (1.0f + expf(-x)); }
__device__ __forceinline__ float oneplusf(float x) {
  return 1.0f + fmaxf(x, 0.0f) + log1pf(expf(-fabsf(x)));
}

// ---- K1: LSTM gates + cell fused. One block per hidden index j; wave g computes
// gate row g*512+j for all 16 batches; then 16 threads finish the cell -> h.
__global__ void k_gates_lstm(const float* __restrict__ task, const float* __restrict__ prev_reads,
                             const float* __restrict__ h_prev, const float* __restrict__ c_prev,
                             const float* __restrict__ W_ih, const float* __restrict__ W_hh,
                             const float* __restrict__ b_lstm, float* __restrict__ ws) {
  int tid = threadIdx.x, lane = tid & 63, wave = tid >> 6;
  int j = blockIdx.x;            // 0..511
  int row = wave * HH + j;       // gate row in [0,2048)
  __shared__ float gv[4][16];
  float acc[16];
#pragma unroll
  for (int b = 0; b < 16; b++) acc[b] = 0.f;
#pragma unroll
  for (int s = 0; s < 5; s++) {
    int k = s * 64 + lane;
    float wv = W_ih[(size_t)row * CIN + k];
    if (s == 0) {
#pragma unroll
      for (int b = 0; b < 16; b++) acc[b] += wv * task[b * 64 + k];
    } else {
#pragma unroll
      for (int b = 0; b < 16; b++) acc[b] += wv * prev_reads[b * 256 + (k - 64)];
    }
  }
#pragma unroll
  for (int s = 0; s < 8; s++) {
    int k = s * 64 + lane;
    float wv = W_hh[(size_t)row * HH + k];
#pragma unroll
    for (int b = 0; b < 16; b++) acc[b] += wv * h_prev[b * HH + k];
  }
#pragma unroll
  for (int b = 0; b < 16; b++) {
#pragma unroll
    for (int off = 32; off >= 1; off >>= 1) acc[b] += __shfl_xor(acc[b], off);
  }
  float val = 0.f;
#pragma unroll
  for (int b = 0; b < 16; b++) if (lane == b) val = acc[b];
  if (lane < 16) gv[wave][lane] = val + b_lstm[row];
  __syncthreads();
  if (tid < 16) {
    int b = tid;
    float gi = gv[0][b], gf = gv[1][b], gg = gv[2][b], go = gv[3][b];
    float c = sigf(gf) * c_prev[b * HH + j] + sigf(gi) * tanhf(gg);
    ws[WS_H + (size_t)b * HH + j] = sigf(go) * tanhf(c);
  }
}

// ---- K2: out_raw = h @ W_out^T + b_out, fused parse (one wave per row j<535)
__global__ void k_outproj_parse(const float* __restrict__ W_out, const float* __restrict__ b_out,
                                float* __restrict__ ws) {
  int tid = threadIdx.x, lane = tid & 63, wave = tid >> 6;
  int j = blockIdx.x * 4 + wave;
  if (j >= COUT) return;
  float acc[16];
#pragma unroll
  for (int b = 0; b < 16; b++) acc[b] = 0.f;
#pragma unroll
  for (int s = 0; s < 8; s++) {
    int k = s * 64 + lane;
    float wv = W_out[j * HH + k];
#pragma unroll
    for (int b = 0; b < 16; b++) acc[b] += wv * ws[WS_H + (size_t)b * HH + k];
  }
#pragma unroll
  for (int b = 0; b < 16; b++) {
#pragma unroll
    for (int off = 32; off >= 1; off >>= 1) acc[b] += __shfl_xor(acc[b], off);
  }
  float bias = b_out[j];
  float val = 0.f;
#pragma unroll
  for (int b = 0; b < 16; b++) if (lane == b) val = acc[b];
  if (lane < 16) {
    int b = lane;
    float v = val + bias;
    ws[WS_OUTR + (size_t)b * COUT + j] = v; // raw kept for read-mode softmax
    if (j < 64)       ws[WS_TASK + b * 64 + j] = sigf(v);
    else if (j < 320) ws[WS_RKEYS + b * 256 + (j - 64)] = sigf(v);
    else if (j < 324) ws[WS_RBETA + b * 4 + (j - 320)] = oneplusf(v);
    else if (j < 328) ws[WS_FGATE + b * 4 + (j - 324)] = sigf(v);
    else if (j < 392) ws[WS_WKEY + b * 64 + (j - 328)] = sigf(v);
    else if (j == 392) ws[WS_WBETA + b] = oneplusf(v);
    else if (j < 457) ws[WS_ERASE + b * 64 + (j - 393)] = sigf(v);
    else if (j < 521) ws[WS_WVEC + b * 64 + (j - 457)] = sigf(v);
    else if (j == 521) ws[WS_AGATE + b] = sigf(v);
    else if (j == 522) ws[WS_WGATE + b] = sigf(v);
  }
}

// ---- K3: content scores + softmax, one block per (b,key) (fused)
__global__ void __launch_bounds__(1024) k_content(const float* __restrict__ memory,
                                                  float* __restrict__ ws) {
  int bk = blockIdx.x; // b*5+k
  int b = bk / 5, k = bk % 5;
  int t = threadIdx.x, lane = t & 63, wave = t >> 6;
  __shared__ __align__(16) float kb[64];
  __shared__ float sc[NN];
  __shared__ float red[16];
  __shared__ float skn, sbeta;
  if (t < 64) kb[t] = (k < 4) ? ws[WS_RKEYS + b * 256 + k * 64 + t] : ws[WS_WKEY + b * 64 + t];
  if (t == 64) sbeta = (k < 4) ? ws[WS_RBETA + b * 4 + k] : ws[WS_WBETA + b];
  __syncthreads();
  if (wave == 0) {
    float kv = kb[lane];
    float ss = kv * kv;
#pragma unroll
    for (int off = 32; off >= 1; off >>= 1) ss += __shfl_xor(ss, off);
    if (lane == 0) skn = sqrtf(ss);
  }
  __syncthreads();
  float kn = skn, beta = sbeta;
  int r = lane >> 4, c = lane & 15;
  float4 key4 = *reinterpret_cast<const float4*>(&kb[c * 4]);
  for (int i = 0; i < 32; i++) {
    int n = wave * 128 + i * 4 + r;
    float4 v = *reinterpret_cast<const float4*>(&memory[((size_t)b * NN + n) * MM + c * 4]);
    float d = v.x * key4.x + v.y * key4.y + v.z * key4.z + v.w * key4.w;
    float s2 = v.x * v.x + v.y * v.y + v.z * v.z + v.w * v.w;
#pragma unroll
    for (int off = 1; off <= 8; off <<= 1) {
      d += __shfl_xor(d, off);
      s2 += __shfl_xor(s2, off);
    }
    if (c == 0) sc[n] = beta * d / (kn * sqrtf(s2) + 1e-8f);
  }
  __syncthreads();
  float v0 = sc[t], v1 = sc[t + 1024];
  float mx = fmaxf(v0, v1);
#pragma unroll
  for (int off = 32; off >= 1; off >>= 1) mx = fmaxf(mx, __shfl_xor(mx, off));
  if (lane == 0) red[wave] = mx;
  __syncthreads();
  mx = red[0];
  for (int w2 = 1; w2 < 16; w2++) mx = fmaxf(mx, red[w2]);
  float e0 = expf(v0 - mx), e1 = expf(v1 - mx);
  float s = e0 + e1;
#pragma unroll
  for (int off = 32; off >= 1; off >>= 1) s += __shfl_xor(s, off);
  __syncthreads();
  if (lane == 0) red[wave] = s;
  __syncthreads();
  s = 0.f;
  for (int w2 = 0; w2 < 16; w2++) s += red[w2];
  float inv = 1.f / s;
  float* dst = ws + WS_CONT + (size_t)bk * NN;
  dst[t] = e0 * inv;
  dst[t + 1024] = e1 * inv;
}

// ---- K4: usage + allocation (bitonic sort) + write weights + p_new, one block per b
__global__ void __launch_bounds__(1024) k_write_path(
    const float* __restrict__ prw, const float* __restrict__ pu,
    const float* __restrict__ pww, const float* __restrict__ prec,
    float* __restrict__ ws, float* __restrict__ out) {
  int b = blockIdx.x, t = threadIdx.x, lane = t & 63, wave = t >> 6;
  __shared__ float sv[NN];
  __shared__ int si[NN];
  __shared__ float al[NN];
  __shared__ float wred[16];
  float fg[4];
#pragma unroll
  for (int r = 0; r < 4; r++) fg[r] = ws[WS_FGATE + b * 4 + r];
#pragma unroll
  for (int e = 0; e < 2; e++) {
    int n = t + e * 1024;
    float psi = 1.f;
#pragma unroll
    for (int r = 0; r < 4; r++) psi *= (1.f - fg[r] * prw[((size_t)b * 4 + r) * NN + n]);
    float a = pu[(size_t)b * NN + n], w = pww[(size_t)b * NN + n];
    float u = (a + w - a * w) * psi;
    out[O_USAGE + (size_t)b * NN + n] = u;
    sv[n] = u;
    si[n] = n;
  }
  __syncthreads();
  for (int k = 2; k <= NN; k <<= 1) {
    for (int j = k >> 1; j > 0; j >>= 1) {
#pragma unroll
      for (int e = 0; e < 2; e++) {
        int idx = t + e * 1024;
        int l = idx ^ j;
        if (l > idx) {
          bool up = ((idx & k) == 0);
          float va = sv[idx], vb = sv[l];
          int ia = si[idx], ib = si[l];
          bool lessBA = (vb < va) || (vb == va && ib < ia);
          if (up ? lessBA : !lessBA) { sv[idx] = vb; sv[l] = va; si[idx] = ib; si[l] = ia; }
        }
      }
      __syncthreads();
    }
  }
  float u0 = sv[2 * t], u1 = sv[2 * t + 1];
  int i0 = si[2 * t], i1 = si[2 * t + 1];
  float lp = u0 * u1;
  float x = lp;
#pragma unroll
  for (int off = 1; off < 64; off <<= 1) {
    float y = __shfl_up(x, off);
    if (lane >= off) x *= y;
  }
  if (lane == 63) wred[wave] = x;
  float ex = __shfl_up(x, 1);
  if (lane == 0) ex = 1.f;
  __syncthreads();
  float base = 1.f;
  for (int w2 = 0; w2 < wave; w2++) base *= wred[w2];
  float E = base * ex;
  al[i0] = (1.f - u0) * E;
  E *= u0;
  al[i1] = (1.f - u1) * E;
  __syncthreads();
  float ag = ws[WS_AGATE + b], wg = ws[WS_WGATE + b];
  float wwv[2], ssum = 0.f;
#pragma unroll
  for (int e = 0; e < 2; e++) {
    int n = t + e * 1024;
    float cw = ws[WS_CONT + ((size_t)b * 5 + 4) * NN + n];
    wwv[e] = wg * (ag * al[n] + (1.f - ag) * cw);
    ws[WS_WW + (size_t)b * NN + n] = wwv[e];
    ssum += wwv[e];
  }
#pragma unroll
  for (int off = 32; off >= 1; off >>= 1) ssum += __shfl_xor(ssum, off);
  __syncthreads();
  if (lane == 0) wred[wave] = ssum;
  __syncthreads();
  float tot = 0.f;
  for (int w2 = 0; w2 < 16; w2++) tot += wred[w2];
  float om = 1.f - tot;
#pragma unroll
  for (int e = 0; e < 2; e++) {
    int n = t + e * 1024;
    out[O_PNEW + (size_t)b * NN + n] = om * prec[(size_t)b * NN + n] + wwv[e];
  }
}

// ---- K5: fused streaming pass over L: fwd_w, bwd partials, link_new, memory_new.
// 512 threads (8 waves), one full 8KB row per iteration, nontemporal L/link traffic.
__global__ void __launch_bounds__(512) k_link(const float* __restrict__ L,
                                              const float* __restrict__ wprev,
                                              const float* __restrict__ mem,
                                              float* __restrict__ ws, float* __restrict__ out) {
  int b = blockIdx.y, chunk = blockIdx.x;
  int i0 = chunk * ROWS;
  int tid = threadIdx.x, lane = tid & 63, wave = tid >> 6; // 8 waves
  __shared__ float wwrow[ROWS];
  __shared__ float wprow[4][ROWS];
  __shared__ float fpart[8][4][ROWS]; // 4 KB
  if (tid < ROWS) wwrow[tid] = ws[WS_WW + (size_t)b * NN + i0 + tid];
  if (tid >= 64 && tid < 64 + 4 * ROWS) {
    int r = (tid - 64) >> 5, ii = (tid - 64) & 31;
    wprow[r][ii] = wprev[((size_t)b * 4 + r) * NN + i0 + ii];
  }
  int j = tid * 4; // fixed 4 columns per thread
  f32x4 wp[4], pn, wwj;
#pragma unroll
  for (int r = 0; r < 4; r++)
    wp[r] = *reinterpret_cast<const f32x4*>(&wprev[((size_t)b * 4 + r) * NN + j]);
  pn = *reinterpret_cast<const f32x4*>(&out[O_PNEW + (size_t)b * NN + j]);
  wwj = *reinterpret_cast<const f32x4*>(&ws[WS_WW + (size_t)b * NN + j]);
  __syncthreads();
  // fused memory_new for rows i0..i0+ROWS-1 (ROWS*64 = 2048 elems)
#pragma unroll
  for (int e = 0; e < 4; e++) {
    int idx = e * 512 + tid;
    int ii = idx >> 6, m = idx & 63;
    size_t g = ((size_t)b * NN + i0 + ii) * MM + m;
    float wwv = wwrow[ii];
    out[O_MEM + g] = mem[g] * (1.f - wwv * ws[WS_ERASE + b * 64 + m]) + wwv * ws[WS_WVEC + b * 64 + m];
  }
  f32x4 bacc[4];
#pragma unroll
  for (int r = 0; r < 4; r++) bacc[r] = (f32x4)(0.f);
  const float* Lb = L + (size_t)b * NN * NN;
  float* linkb = out + O_LINK + (size_t)b * NN * NN;
  for (int ii = 0; ii < ROWS; ii++) {
    int i = i0 + ii;
    const f32x4* lr = reinterpret_cast<const f32x4*>(Lb + (size_t)i * NN);
    f32x4 v = __builtin_nontemporal_load(lr + tid);
    // fwd partial dots (per-wave 256-column slice), reduce across 64 lanes
    float f0 = v[0] * wp[0][0] + v[1] * wp[0][1] + v[2] * wp[0][2] + v[3] * wp[0][3];
    float f1 = v[0] * wp[1][0] + v[1] * wp[1][1] + v[2] * wp[1][2] + v[3] * wp[1][3];
    float f2 = v[0] * wp[2][0] + v[1] * wp[2][1] + v[2] * wp[2][2] + v[3] * wp[2][3];
    float f3 = v[0] * wp[3][0] + v[1] * wp[3][1] + v[2] * wp[3][2] + v[3] * wp[3][3];
#pragma unroll
    for (int off = 32; off >= 1; off >>= 1) {
      f0 += __shfl_xor(f0, off);
      f1 += __shfl_xor(f1, off);
      f2 += __shfl_xor(f2, off);
      f3 += __shfl_xor(f3, off);
    }
    if (lane == 0) {
      fpart[wave][0][ii] = f0; fpart[wave][1][ii] = f1;
      fpart[wave][2][ii] = f2; fpart[wave][3][ii] = f3;
    }
    // bwd: column accumulation
#pragma unroll
    for (int r = 0; r < 4; r++) {
      float w = wprow[r][ii];
      bacc[r][0] += w * v[0]; bacc[r][1] += w * v[1];
      bacc[r][2] += w * v[2]; bacc[r][3] += w * v[3];
    }
    // link update + diagonal zero
    float wwi = wwrow[ii];
    f32x4 o;
    o[0] = (1.f - wwi - wwj[0]) * v[0] + wwi * pn[0];
    o[1] = (1.f - wwi - wwj[1]) * v[1] + wwi * pn[1];
    o[2] = (1.f - wwi - wwj[2]) * v[2] + wwi * pn[2];
    o[3] = (1.f - wwi - wwj[3]) * v[3] + wwi * pn[3];
    if (i == j)     o[0] = 0.f;
    if (i == j + 1) o[1] = 0.f;
    if (i == j + 2) o[2] = 0.f;
    if (i == j + 3) o[3] = 0.f;
    __builtin_nontemporal_store(o, reinterpret_cast<f32x4*>(linkb + (size_t)i * NN) + tid);
  }
  __syncthreads();
  if (tid < 4 * ROWS) {
    int r = tid >> 5, ii = tid & 31;
    float s = 0.f;
#pragma unroll
    for (int w2 = 0; w2 < 8; w2++) s += fpart[w2][r][ii];
    ws[WS_FWD + ((size_t)b * 4 + r) * NN + i0 + ii] = s;
  }
#pragma unroll
  for (int r = 0; r < 4; r++)
    *reinterpret_cast<f32x4*>(
        &ws[WS_BPART + (((size_t)b * CHUNKS + chunk) * 4 + r) * NN + j]) = bacc[r];
}

// ---- K6: bwd chunk-reduce + read modes + read_w + read partial dots (fused)
__global__ void __launch_bounds__(256) k_readrw(const float* __restrict__ memory,
                                                float* __restrict__ ws, float* __restrict__ out) {
  int b = blockIdx.x >> 3, chunk = blockIdx.x & 7;
  int n0 = chunk * 256;
  int t = threadIdx.x, lane = t & 63, wave = t >> 6;
  __shared__ float fm[4][3];
  __shared__ float rwl[4][256];
  __shared__ float part[4][4][64];
  if (t < 4) {
    const float* o = ws + WS_OUTR + (size_t)b * COUT + 523 + t * 3;
    float a = o[0], bb = o[1], cc = o[2];
    float m = fmaxf(a, fmaxf(bb, cc));
    float ea = expf(a - m), eb = expf(bb - m), ec = expf(cc - m);
    float iv = 1.f / (ea + eb + ec);
    fm[t][0] = ea * iv; fm[t][1] = eb * iv; fm[t][2] = ec * iv;
  }
  __syncthreads();
#pragma unroll
  for (int r = 0; r < 4; r++) {
    int n = n0 + t;
    float bwd = 0.f;
    for (int c2 = 0; c2 < CHUNKS; c2++)
      bwd += ws[WS_BPART + (((size_t)b * CHUNKS + c2) * 4 + r) * NN + n];
    float fwd = ws[WS_FWD + ((size_t)b * 4 + r) * NN + n];
    float cont = ws[WS_CONT + ((size_t)b * 5 + r) * NN + n];
    float rw = fm[r][0] * bwd + fm[r][1] * cont + fm[r][2] * fwd;
    out[O_READW + ((size_t)b * 4 + r) * NN + n] = rw;
    rwl[r][t] = rw;
  }
  __syncthreads();
  float acc[4] = {0.f, 0.f, 0.f, 0.f};
  for (int ii = 0; ii < 64; ii++) {
    int nl = wave * 64 + ii;
    float mv = memory[((size_t)b * NN + n0 + nl) * MM + lane];
#pragma unroll
    for (int r = 0; r < 4; r++) acc[r] += rwl[r][nl] * mv;
  }
#pragma unroll
  for (int r = 0; r < 4; r++) part[wave][r][lane] = acc[r];
  __syncthreads();
  { int r = t >> 6, m = t & 63;
    float s = part[0][r][m] + part[1][r][m] + part[2][r][m] + part[3][r][m];
    ws[WS_RPART + ((size_t)(b * 8 + chunk)) * 256 + t] = s; }
}

// ---- K7: reduce read partials + read projection + final output
__global__ void k_final(const float* __restrict__ W_read, const float* __restrict__ b_read,
                        const float* __restrict__ ws, float* __restrict__ out) {
  int b = blockIdx.x, t = threadIdx.x, lane = t & 63, wave = t >> 6;
  __shared__ float rds[256];
  float s = 0.f;
  for (int c = 0; c < 8; c++) s += ws[WS_RPART + ((size_t)(b * 8 + c)) * 256 + t];
  rds[t] = s;
  __syncthreads();
  for (int oi = 0; oi < 16; oi++) {
    int o = wave * 16 + oi;
    float acc = 0.f;
#pragma unroll
    for (int s2 = 0; s2 < 4; s2++) {
      int kk = s2 * 64 + lane;
      acc += W_read[o * 256 + kk] * rds[kk];
    }
#pragma unroll
    for (int off = 32; off >= 1; off >>= 1) acc += __shfl_xor(acc, off);
    if (lane == 0) {
      float ro = sigf(acc + b_read[o]);
      out[O_OUT + b * 64 + o] = sigf(ro + ws[WS_TASK + b * 64 + o]);
    }
  }
}

extern "C" void kernel_launch(void* const* d_in, const int* in_sizes, int n_in,
                              void* d_out, int out_size, void* d_ws, size_t ws_size,
                              hipStream_t stream) {
  (void)in_sizes; (void)n_in; (void)out_size; (void)ws_size;
  const float* task   = (const float*)d_in[0];
  const float* memory = (const float*)d_in[1];
  const float* links  = (const float*)d_in[2];
  const float* preads = (const float*)d_in[3];
  const float* prw    = (const float*)d_in[4];
  const float* pusage = (const float*)d_in[5];
  const float* pww    = (const float*)d_in[6];
  const float* prec   = (const float*)d_in[7];
  const float* h_prev = (const float*)d_in[8];
  const float* c_prev = (const float*)d_in[9];
  const float* W_ih   = (const float*)d_in[10];
  const float* W_hh   = (const float*)d_in[11];
  const float* b_lstm = (const float*)d_in[12];
  const float* W_out  = (const float*)d_in[13];
  const float* b_out  = (const float*)d_in[14];
  const float* W_read = (const float*)d_in[15];
  const float* b_read = (const float*)d_in[16];
  float* out = (float*)d_out;
  float* ws  = (float*)d_ws;

  k_gates_lstm<<<512, 256, 0, stream>>>(task, preads, h_prev, c_prev, W_ih, W_hh, b_lstm, ws);
  k_outproj_parse<<<134, 256, 0, stream>>>(W_out, b_out, ws);
  k_content<<<80, 1024, 0, stream>>>(memory, ws);
  k_write_path<<<16, 1024, 0, stream>>>(prw, pusage, pww, prec, ws, out);
  k_link<<<dim3(CHUNKS, BB), 512, 0, stream>>>(links, prw, memory, ws, out);
  k_readrw<<<128, 256, 0, stream>>>(memory, ws, out);
  k_final<<<16, 256, 0, stream>>>(W_read, b_read, ws, out);
}